// Round 1
// baseline (1198.329 us; speedup 1.0000x reference)
//
#include <hip/hip_runtime.h>
#include <cstdint>

// Problem constants (hard-coded in the reference module)
static constexpr int N = 716;
static constexpr int T = 12;
static constexpr int C = 10;
static constexpr int B = 64;
static constexpr int E = 11441;

// DEG[n] = 8 + (n % 17); offsets in closed form.
__device__ __forceinline__ int node_off(int n) {
    int q = n / 17, r = n % 17;
    return 8 * n + 136 * q + (r * (r - 1)) / 2;
}

// ---------------- Kernel A: wv[e] = sum_c W3[c]*W_flat[c,e]; bb[n] = sum_c W3[c]*bias[n,c]
__global__ void k_pre(const float* __restrict__ W_flat, const float* __restrict__ bias,
                      const float* __restrict__ W3, float* __restrict__ wv, float* __restrict__ bb) {
    int i = blockIdx.x * blockDim.x + threadIdx.x;
    float w3[C];
#pragma unroll
    for (int c = 0; c < C; ++c) w3[c] = W3[c];
    if (i < E) {
        float s = 0.f;
#pragma unroll
        for (int c = 0; c < C; ++c) s += w3[c] * W_flat[c * E + i];
        wv[i] = s;
    }
    if (i < N) {
        float s = 0.f;
#pragma unroll
        for (int c = 0; c < C; ++c) s += w3[c] * bias[i * C + c];
        bb[i] = s;
    }
}

// ---------------- Kernel: u[b,e] = sum_t vals[b,t,e]*W1[t]
__global__ void k_u(const float* __restrict__ vals, const float* __restrict__ W1,
                    float* __restrict__ u) {
    int i = blockIdx.x * blockDim.x + threadIdx.x;
    if (i >= B * E) return;
    int b = i / E, e = i - b * E;
    const float* p = vals + (size_t)b * T * E + e;
    float s = 0.f;
#pragma unroll
    for (int t = 0; t < T; ++t) s += p[(size_t)t * E] * W1[t];
    u[i] = s;
}

// ---------------- Kernel: rhs[b,n,t] = bb[n] + sum_{e in node n} vals[b,t,e]*wv[e]
__global__ void k_rhs(const float* __restrict__ vals, const float* __restrict__ wv,
                      const float* __restrict__ bb, float* __restrict__ rhs) {
    int i = blockIdx.x * blockDim.x + threadIdx.x;
    if (i >= B * N * T) return;
    int t = i % T;
    int bn = i / T;
    int n = bn % N;
    int b = bn / N;
    int off = node_off(n);
    int deg = 8 + (n % 17);
    const float* p = vals + (size_t)b * T * E + (size_t)t * E + off;
    const float* w = wv + off;
    float s = bb[n];
    for (int e = 0; e < deg; ++e) s += p[e] * w[e];
    rhs[i] = s;
}

// ---------------- Kernel: a[b,n,c] = bias[n,c]*sum(W1) + sum_{e in node n} u[b,e]*W_flat[c,e]
__global__ void k_a(const float* __restrict__ u, const float* __restrict__ W_flat,
                    const float* __restrict__ bias, const float* __restrict__ W1,
                    float* __restrict__ a) {
    int i = blockIdx.x * blockDim.x + threadIdx.x;
    if (i >= B * N * C) return;
    int c = i % C;
    int bn = i / C;
    int n = bn % N;
    int b = bn / N;
    float S1 = 0.f;
#pragma unroll
    for (int t = 0; t < T; ++t) S1 += W1[t];
    int off = node_off(n);
    int deg = 8 + (n % 17);
    const float* up = u + (size_t)b * E + off;
    const float* wp = W_flat + (size_t)c * E + off;
    float s = bias[n * C + c] * S1;
    for (int e = 0; e < deg; ++e) s += up[e] * wp[e];
    a[i] = s;
}

// ---------------- Kernel: lhs[b,n,t] = sum_c a[b,n,c]*W2[c,t]
__global__ void k_lhs(const float* __restrict__ a, const float* __restrict__ W2,
                      float* __restrict__ lhs) {
    int i = blockIdx.x * blockDim.x + threadIdx.x;
    if (i >= B * N * T) return;
    int t = i % T;
    int bn = i / T;
    float s = 0.f;
#pragma unroll
    for (int c = 0; c < C; ++c) s += a[(size_t)bn * C + c] * W2[c * T + t];
    lhs[i] = s;
}

// ---------------- Kernel: sig[b,n,m] = sigmoid(sum_t lhs[b,n,t]*rhs[b,m,t] + bs[n,m])
__global__ void __launch_bounds__(256) k_prod(const float* __restrict__ lhs,
                                              const float* __restrict__ rhs,
                                              const float* __restrict__ bs,
                                              float* __restrict__ sig) {
    int bn = blockIdx.x;            // b*N + n
    int b = bn / N;
    int n = bn - b * N;
    int m = blockIdx.y * 256 + threadIdx.x;
    __shared__ float l[T];
    if (threadIdx.x < T) l[threadIdx.x] = lhs[(size_t)bn * T + threadIdx.x];
    __syncthreads();
    if (m >= N) return;
    const float* rp = rhs + ((size_t)b * N + m) * T;
    float s = 0.f;
#pragma unroll
    for (int t = 0; t < T; ++t) s += l[t] * rp[t];
    s += bs[(size_t)n * N + m];
    sig[(size_t)b * N * N + (size_t)n * N + m] = 1.f / (1.f + expf(-s));
}

// ---------------- Kernel: S[b,n,k] = sum_m Vs[n,m]*sig[b,m,k]   (fp32 tiled GEMM)
// 64x64 tile, BK=16, 256 threads, 4x4 micro-tile.
__global__ void __launch_bounds__(256) k_gemm(const float* __restrict__ Vs,
                                              const float* __restrict__ sig,
                                              float* __restrict__ S) {
    __shared__ float As[16][64];  // As[m_local][n_local] = Vs[n0+n_local, m0+m_local]
    __shared__ float Bs[16][64];  // Bs[m_local][k_local] = sig[b, m0+m_local, k0+k_local]

    int kt = blockIdx.x, nt = blockIdx.y, b = blockIdx.z;
    int n0 = nt * 64, k0 = kt * 64;
    int tid = threadIdx.x;

    int tr = tid / 16;       // 0..15 -> row group
    int tc = tid % 16;       // 0..15 -> col group

    // load indices for As: each thread loads one float4 from a Vs row
    int ai = tid / 4;              // 0..63 : n_local
    int aj = (tid % 4) * 4;        // 0,4,8,12 : m_local
    // load indices for Bs:
    int bj = tid / 16;             // 0..15 : m_local
    int bk = (tid % 16) * 4;       // 0..60 : k_local

    const float* sigb = sig + (size_t)b * N * N;

    float acc[4][4];
#pragma unroll
    for (int i = 0; i < 4; ++i)
#pragma unroll
        for (int j = 0; j < 4; ++j) acc[i][j] = 0.f;

    for (int m0 = 0; m0 < N; m0 += 16) {
        // stage As (transposed)
        {
            int row = n0 + ai, col = m0 + aj;
            float4 v = make_float4(0.f, 0.f, 0.f, 0.f);
            if (row < N && col < N) v = *(const float4*)(Vs + (size_t)row * N + col);
            As[aj + 0][ai] = v.x;
            As[aj + 1][ai] = v.y;
            As[aj + 2][ai] = v.z;
            As[aj + 3][ai] = v.w;
        }
        // stage Bs
        {
            int row = m0 + bj, col = k0 + bk;
            float4 v = make_float4(0.f, 0.f, 0.f, 0.f);
            if (row < N && col < N) v = *(const float4*)(sigb + (size_t)row * N + col);
            *(float4*)&Bs[bj][bk] = v;
        }
        __syncthreads();

#pragma unroll
        for (int kk = 0; kk < 16; ++kk) {
            float4 av = *(const float4*)&As[kk][tr * 4];
            float4 bv = *(const float4*)&Bs[kk][tc * 4];
            float avv[4] = {av.x, av.y, av.z, av.w};
            float bvv[4] = {bv.x, bv.y, bv.z, bv.w};
#pragma unroll
            for (int i = 0; i < 4; ++i)
#pragma unroll
                for (int j = 0; j < 4; ++j) acc[i][j] += avv[i] * bvv[j];
        }
        __syncthreads();
    }

    float* Sb = S + (size_t)b * N * N;
#pragma unroll
    for (int i = 0; i < 4; ++i) {
        int row = n0 + tr * 4 + i;
        if (row >= N) continue;
#pragma unroll
        for (int j = 0; j < 4; ++j) {
            int col = k0 + tc * 4 + j;
            if (col < N) Sb[(size_t)row * N + col] = acc[i][j];
        }
    }
}

// ---------------- Kernel: online softmax stats over n (axis=1), per (b,k)
__global__ void k_stats(const float* __restrict__ S, float* __restrict__ smax,
                        float* __restrict__ ssum) {
    int i = blockIdx.x * blockDim.x + threadIdx.x;
    if (i >= B * N) return;
    int b = i / N, k = i - b * N;
    const float* p = S + (size_t)b * N * N + k;
    float m = -1e30f, s = 0.f;
    for (int n = 0; n < N; ++n) {
        float v = p[(size_t)n * N];
        float nm = fmaxf(m, v);
        s = s * expf(m - nm) + expf(v - nm);
        m = nm;
    }
    smax[i] = m;
    ssum[i] = s;
}

// ---------------- Kernel: out[b,n,k] = exp(S-max)/sum  (in-place on d_out)
__global__ void k_norm(float* __restrict__ S, const float* __restrict__ smax,
                       const float* __restrict__ ssum) {
    size_t i = (size_t)blockIdx.x * blockDim.x + threadIdx.x;
    if (i >= (size_t)B * N * N) return;
    size_t b = i / ((size_t)N * N);
    size_t rem = i - b * (size_t)N * N;
    int k = (int)(rem % N);
    float m = smax[b * N + k];
    float s = ssum[b * N + k];
    S[i] = expf(S[i] - m) / s;
}

extern "C" void kernel_launch(void* const* d_in, const int* in_sizes, int n_in,
                              void* d_out, int out_size, void* d_ws, size_t ws_size,
                              hipStream_t stream) {
    const float* vals   = (const float*)d_in[0];  // [B,T,E]
    const float* W_flat = (const float*)d_in[1];  // [C,E]
    const float* bias   = (const float*)d_in[2];  // [N,C]
    const float* W1     = (const float*)d_in[3];  // [T]
    const float* W2     = (const float*)d_in[4];  // [C,T]
    const float* W3     = (const float*)d_in[5];  // [C]
    const float* bs     = (const float*)d_in[6];  // [1,N,N]
    const float* Vs     = (const float*)d_in[7];  // [N,N]
    // d_in[8] = seg_ids, unused (closed-form offsets)
    float* out = (float*)d_out;                   // [B,N,N] -> holds S, then softmaxed in place
    float* ws = (float*)d_ws;

    // workspace layout (floats), 16B-aligned segments
    float* sig  = ws;                       // B*N*N = 32,806,784
    float* u    = sig  + (size_t)B * N * N; // B*E   = 732,224
    float* rhs  = u    + (size_t)B * E;     // B*N*T = 549,888
    float* lhs  = rhs  + (size_t)B * N * T; // B*N*T = 549,888
    float* a    = lhs  + (size_t)B * N * T; // B*N*C = 458,240
    float* wv   = a    + (size_t)B * N * C; // pad to 11,444
    float* bb   = wv   + 11444;             // 716
    float* smax = bb   + N;                 // B*N = 45,824
    float* ssum = smax + (size_t)B * N;     // B*N = 45,824

    k_pre<<<(E + 255) / 256, 256, 0, stream>>>(W_flat, bias, W3, wv, bb);
    k_u<<<(B * E + 255) / 256, 256, 0, stream>>>(vals, W1, u);
    k_rhs<<<(B * N * T + 255) / 256, 256, 0, stream>>>(vals, wv, bb, rhs);
    k_a<<<(B * N * C + 255) / 256, 256, 0, stream>>>(u, W_flat, bias, W1, a);
    k_lhs<<<(B * N * T + 255) / 256, 256, 0, stream>>>(a, W2, lhs);

    dim3 gp(B * N, (N + 255) / 256);
    k_prod<<<gp, 256, 0, stream>>>(lhs, rhs, bs, sig);

    dim3 gg((N + 63) / 64, (N + 63) / 64, B);
    k_gemm<<<gg, 256, 0, stream>>>(Vs, sig, out);

    k_stats<<<(B * N + 255) / 256, 256, 0, stream>>>(out, smax, ssum);

    size_t tot = (size_t)B * N * N;
    k_norm<<<(int)((tot + 255) / 256), 256, 0, stream>>>(out, smax, ssum);
}

// Round 2
// 549.755 us; speedup vs baseline: 2.1798x; 2.1798x over previous
//
#include <hip/hip_runtime.h>
#include <cstdint>

using u16 = unsigned short;

// Problem constants
static constexpr int N = 716;
static constexpr int T = 12;
static constexpr int C = 10;
static constexpr int B = 64;
static constexpr int E = 11441;

static constexpr int KP = 768;           // padded contraction dim (multiple of 64)
static constexpr int BK = 64;            // K-step
static constexpr int NSTEP = KP / BK;    // 12
static constexpr int NBC = 32;           // batch chunk

typedef __attribute__((ext_vector_type(8))) __bf16 bf16x8;
typedef __attribute__((ext_vector_type(4))) float f32x4;

__device__ __forceinline__ int node_off(int n) {
    int q = n / 17, r = n % 17;
    return 8 * n + 136 * q + (r * (r - 1)) / 2;
}

__device__ __forceinline__ u16 f2bf(float x) {
    unsigned u = __float_as_uint(x);
    unsigned r = (u + 0x7fffu + ((u >> 16) & 1u)) >> 16;
    return (u16)r;
}
__device__ __forceinline__ float bf2f(u16 h) {
    return __uint_as_float(((unsigned)h) << 16);
}

typedef const __attribute__((address_space(1))) unsigned int* gp1_t;
typedef __attribute__((address_space(3))) unsigned int* lp3_t;
__device__ __forceinline__ void gload16(const void* g, void* l) {
    __builtin_amdgcn_global_load_lds((gp1_t)g, (lp3_t)l, 16, 0, 0);
}

// ---------------- small prologue kernels (unchanged from round 1) ----------------
__global__ void k_pre(const float* __restrict__ W_flat, const float* __restrict__ bias,
                      const float* __restrict__ W3, float* __restrict__ wv, float* __restrict__ bb) {
    int i = blockIdx.x * blockDim.x + threadIdx.x;
    float w3[C];
#pragma unroll
    for (int c = 0; c < C; ++c) w3[c] = W3[c];
    if (i < E) {
        float s = 0.f;
#pragma unroll
        for (int c = 0; c < C; ++c) s += w3[c] * W_flat[c * E + i];
        wv[i] = s;
    }
    if (i < N) {
        float s = 0.f;
#pragma unroll
        for (int c = 0; c < C; ++c) s += w3[c] * bias[i * C + c];
        bb[i] = s;
    }
}

__global__ void k_u(const float* __restrict__ vals, const float* __restrict__ W1,
                    float* __restrict__ u) {
    int i = blockIdx.x * blockDim.x + threadIdx.x;
    if (i >= B * E) return;
    int b = i / E, e = i - b * E;
    const float* p = vals + (size_t)b * T * E + e;
    float s = 0.f;
#pragma unroll
    for (int t = 0; t < T; ++t) s += p[(size_t)t * E] * W1[t];
    u[i] = s;
}

__global__ void k_rhs(const float* __restrict__ vals, const float* __restrict__ wv,
                      const float* __restrict__ bb, float* __restrict__ rhs) {
    int i = blockIdx.x * blockDim.x + threadIdx.x;
    if (i >= B * N * T) return;
    int t = i % T;
    int bn = i / T;
    int n = bn % N;
    int b = bn / N;
    int off = node_off(n);
    int deg = 8 + (n % 17);
    const float* p = vals + (size_t)b * T * E + (size_t)t * E + off;
    const float* w = wv + off;
    float s = bb[n];
    for (int e = 0; e < deg; ++e) s += p[e] * w[e];
    rhs[i] = s;
}

__global__ void k_a(const float* __restrict__ u, const float* __restrict__ W_flat,
                    const float* __restrict__ bias, const float* __restrict__ W1,
                    float* __restrict__ a) {
    int i = blockIdx.x * blockDim.x + threadIdx.x;
    if (i >= B * N * C) return;
    int c = i % C;
    int bn = i / C;
    int n = bn % N;
    int b = bn / N;
    float S1 = 0.f;
#pragma unroll
    for (int t = 0; t < T; ++t) S1 += W1[t];
    int off = node_off(n);
    int deg = 8 + (n % 17);
    const float* up = u + (size_t)b * E + off;
    const float* wp = W_flat + (size_t)c * E + off;
    float s = bias[n * C + c] * S1;
    for (int e = 0; e < deg; ++e) s += up[e] * wp[e];
    a[i] = s;
}

__global__ void k_lhs(const float* __restrict__ a, const float* __restrict__ W2,
                      float* __restrict__ lhs) {
    int i = blockIdx.x * blockDim.x + threadIdx.x;
    if (i >= B * N * T) return;
    int t = i % T;
    int bn = i / T;
    float s = 0.f;
#pragma unroll
    for (int c = 0; c < C; ++c) s += a[(size_t)bn * C + c] * W2[c * T + t];
    lhs[i] = s;
}

// ---------------- bsT[j][i] = bs[i][j] ----------------
__global__ void k_bsT(const float* __restrict__ bs, float* __restrict__ bsT) {
    int idx = blockIdx.x * blockDim.x + threadIdx.x;
    if (idx >= N * N) return;
    int j = idx / N, i = idx - j * N;
    bsT[(size_t)j * N + i] = bs[(size_t)i * N + j];
}

// ---------------- A planes: Vs -> bf16 hi/lo, [716][768], zero pad cols >=716 ----------------
__global__ void k_preA(const float* __restrict__ Vs, u16* __restrict__ AH, u16* __restrict__ AL) {
    int idx = blockIdx.x * blockDim.x + threadIdx.x;
    if (idx >= N * KP) return;
    int n = idx / KP, ic = idx - n * KP;
    float v = (ic < N) ? Vs[(size_t)n * N + ic] : 0.f;
    u16 hi = f2bf(v);
    AH[idx] = hi;
    AL[idx] = f2bf(v - bf2f(hi));
}

// ---------------- sigT planes: sigT[bz][j][i] = sigmoid(dot(lhs[i],rhs[j]) + bs[i][j]) ----------------
// grid: (3 i-blocks, 45 j-tiles, NBC batches)
__global__ void __launch_bounds__(256) k_prod2(const float* __restrict__ lhs,
                                               const float* __restrict__ rhs,
                                               const float* __restrict__ bsT,
                                               u16* __restrict__ TH, u16* __restrict__ TL,
                                               int b0) {
    __shared__ float rl[16][12];
    int tid = threadIdx.x;
    int bz = blockIdx.z, b = b0 + bz;
    int j0 = blockIdx.y * 16;
    int i = blockIdx.x * 256 + tid;     // 0..767
    if (tid < 192) {
        int jj = tid / 12, t = tid - jj * 12;
        int j = j0 + jj;
        rl[jj][t] = (j < N) ? rhs[((size_t)b * N + j) * T + t] : 0.f;
    }
    __syncthreads();
    float l[12];
    bool live = (i < N);
    if (live) {
        const float4* lp = (const float4*)(lhs + ((size_t)b * N + i) * T);
        float4 a0 = lp[0], a1 = lp[1], a2 = lp[2];
        l[0] = a0.x; l[1] = a0.y; l[2] = a0.z; l[3] = a0.w;
        l[4] = a1.x; l[5] = a1.y; l[6] = a1.z; l[7] = a1.w;
        l[8] = a2.x; l[9] = a2.y; l[10] = a2.z; l[11] = a2.w;
    }
#pragma unroll
    for (int jj = 0; jj < 16; ++jj) {
        int j = j0 + jj;
        if (j >= N) break;
        size_t dst = ((size_t)bz * N + j) * KP + i;
        if (live) {
            float s = bsT[(size_t)j * N + i];
#pragma unroll
            for (int t = 0; t < T; ++t) s = fmaf(l[t], rl[jj][t], s);
            float v = 1.f / (1.f + __expf(-s));
            u16 hi = f2bf(v);
            float lo = v - bf2f(hi);
            TH[dst] = hi;
            TL[dst] = f2bf(lo);
        } else {
            TH[dst] = 0;
            TL[dst] = 0;
        }
    }
}

// ---------------- split-bf16 MFMA GEMM: S[b][n][j] = sum_i Vs[n][i]*sig[b][i][j] ----------------
// A = Vs planes [716][KP] row-major; B^T = sigT planes [NBC][716][KP] row-major.
// 128x128 tile, BK=64, 4 waves (2x2), each wave 64x64 = 4x4 fragments of 16x16x32.
// LDS XOR-swizzle (row&7)<<4 bytes, applied on the global source address (linear LDS dest).
__global__ void __launch_bounds__(256, 2)
k_mfma(const u16* __restrict__ AH, const u16* __restrict__ AL,
       const u16* __restrict__ BH, const u16* __restrict__ BL,
       float* __restrict__ S, int b0) {
    __shared__ u16 lds[4][128 * BK];    // 4 planes x 16 KB = 64 KB
    const int tid = threadIdx.x;
    const int bz = blockIdx.z;
    const int nt = blockIdx.y, jt = blockIdx.x;
    const int n0 = nt * 128, j0 = jt * 128;
    const int lane = tid & 63;
    const int wid = tid >> 6;
    const int wr = wid >> 1, wc = wid & 1;
    const int r = lane & 15, h = lane >> 4;

    const size_t planeB = (size_t)N * KP;
    const u16* srcA[2] = { AH, AL };
    const u16* srcB[2] = { BH + (size_t)bz * planeB, BL + (size_t)bz * planeB };

    // staging: per plane, issue q=0..3; LDS byte = q*4096 + tid*16
    // -> LDS row = q*32 + tid/8 (row stride 128B), col-byte = (tid%8)*16
    // source col-byte = cb ^ ((row&7)<<4)  (inverse of read-side swizzle)
    const int cb_sw = ((tid & 7) * 16) ^ (((tid >> 3) & 7) * 16);
    const int row_base = tid >> 3;

    f32x4 acc[4][4] = {};

    for (int step = 0; step < NSTEP; ++step) {
        const int mb = step * (BK * 2);   // byte offset along a row
#pragma unroll
        for (int p = 0; p < 4; ++p) {
            const int rbase = (p < 2) ? n0 : j0;
            const u16* src = (p < 2) ? srcA[p] : srcB[p - 2];
#pragma unroll
            for (int q = 0; q < 4; ++q) {
                int lrow = q * 32 + row_base;
                int grow = rbase + lrow;
                if (grow > N - 1) grow = N - 1;   // clamp: harmless data, outputs guarded
                const char* g = (const char*)src + (size_t)grow * (KP * 2) + mb + cb_sw;
                gload16(g, (char*)&lds[p][0] + q * 4096 + tid * 16);
            }
        }
        __syncthreads();
#pragma unroll
        for (int kk = 0; kk < 2; ++kk) {
            bf16x8 aHf[4], aLf[4], bHf[4], bLf[4];
#pragma unroll
            for (int f = 0; f < 4; ++f) {
                int arow = wr * 64 + f * 16 + r;
                int aidx = arow * BK + ((kk * 32 + h * 8) ^ ((arow & 7) * 8));
                aHf[f] = *(const bf16x8*)&lds[0][aidx];
                aLf[f] = *(const bf16x8*)&lds[1][aidx];
                int brow = wc * 64 + f * 16 + r;
                int bidx = brow * BK + ((kk * 32 + h * 8) ^ ((brow & 7) * 8));
                bHf[f] = *(const bf16x8*)&lds[2][bidx];
                bLf[f] = *(const bf16x8*)&lds[3][bidx];
            }
#pragma unroll
            for (int fi = 0; fi < 4; ++fi)
#pragma unroll
                for (int fj = 0; fj < 4; ++fj) {
                    acc[fi][fj] = __builtin_amdgcn_mfma_f32_16x16x32_bf16(aHf[fi], bHf[fj], acc[fi][fj], 0, 0, 0);
                    acc[fi][fj] = __builtin_amdgcn_mfma_f32_16x16x32_bf16(aLf[fi], bHf[fj], acc[fi][fj], 0, 0, 0);
                    acc[fi][fj] = __builtin_amdgcn_mfma_f32_16x16x32_bf16(aHf[fi], bLf[fj], acc[fi][fj], 0, 0, 0);
                }
        }
        __syncthreads();
    }

    float* Sb = S + (size_t)(b0 + bz) * N * N;
#pragma unroll
    for (int fi = 0; fi < 4; ++fi) {
        int rg = n0 + wr * 64 + fi * 16 + h * 4;
#pragma unroll
        for (int fj = 0; fj < 4; ++fj) {
            int cg = j0 + wc * 64 + fj * 16 + r;
            if (cg < N) {
#pragma unroll
                for (int qq = 0; qq < 4; ++qq)
                    if (rg + qq < N) Sb[(size_t)(rg + qq) * N + cg] = acc[fi][fj][qq];
            }
        }
    }
}

// ---------------- softmax over axis=1 (rows of S), split into 4 n-chunks ----------------
__global__ void k_stats2(const float* __restrict__ S, float* __restrict__ pmax,
                         float* __restrict__ psum) {
    int j = blockIdx.x * 256 + threadIdx.x;
    int b = blockIdx.y;
    int ch = blockIdx.z;
    if (j >= N) return;
    const float* p = S + (size_t)b * N * N + j;
    int n0 = ch * 179, n1 = n0 + 179;   // 4*179 = 716
    float m = -3.0e38f, s = 0.f;
    for (int n = n0; n < n1; ++n) {
        float v = p[(size_t)n * N];
        float nm = fmaxf(m, v);
        s = s * __expf(m - nm) + __expf(v - nm);
        m = nm;
    }
    pmax[((size_t)ch * B + b) * 720 + j] = m;
    psum[((size_t)ch * B + b) * 720 + j] = s;
}

__global__ void k_comb(const float* __restrict__ pmax, const float* __restrict__ psum,
                       float* __restrict__ smax, float* __restrict__ sinv) {
    int i = blockIdx.x * 256 + threadIdx.x;
    if (i >= B * N) return;
    int b = i / N, j = i - b * N;
    float m = -3.0e38f;
#pragma unroll
    for (int c = 0; c < 4; ++c) m = fmaxf(m, pmax[((size_t)c * B + b) * 720 + j]);
    float s = 0.f;
#pragma unroll
    for (int c = 0; c < 4; ++c)
        s += psum[((size_t)c * B + b) * 720 + j] * __expf(pmax[((size_t)c * B + b) * 720 + j] - m);
    smax[(size_t)b * 720 + j] = m;
    sinv[(size_t)b * 720 + j] = 1.f / s;
}

__global__ void k_norm2(float* __restrict__ S, const float* __restrict__ smax,
                        const float* __restrict__ sinv) {
    size_t idx = (size_t)blockIdx.x * 256 + threadIdx.x;
    if (idx >= (size_t)B * N * (N / 2)) return;
    int jp = (int)(idx % (N / 2));
    size_t bn = idx / (N / 2);
    int n = (int)(bn % N);
    int b = (int)(bn / N);
    size_t base = ((size_t)b * N + n) * N + (size_t)jp * 2;
    float2 v = *(float2*)(S + base);
    int j = jp * 2;
    float m0 = smax[(size_t)b * 720 + j], m1 = smax[(size_t)b * 720 + j + 1];
    float r0 = sinv[(size_t)b * 720 + j], r1 = sinv[(size_t)b * 720 + j + 1];
    v.x = __expf(v.x - m0) * r0;
    v.y = __expf(v.y - m1) * r1;
    *(float2*)(S + base) = v;
}

extern "C" void kernel_launch(void* const* d_in, const int* in_sizes, int n_in,
                              void* d_out, int out_size, void* d_ws, size_t ws_size,
                              hipStream_t stream) {
    const float* vals   = (const float*)d_in[0];  // [B,T,E]
    const float* W_flat = (const float*)d_in[1];  // [C,E]
    const float* bias   = (const float*)d_in[2];  // [N,C]
    const float* W1     = (const float*)d_in[3];  // [T]
    const float* W2     = (const float*)d_in[4];  // [C,T]
    const float* W3     = (const float*)d_in[5];  // [C]
    const float* bs     = (const float*)d_in[6];  // [1,N,N]
    const float* Vs     = (const float*)d_in[7];  // [N,N]
    float* out = (float*)d_out;                   // [B,N,N]

    float* f = (float*)d_ws;
    u16* sigTH = (u16*)f;  f += (size_t)NBC * N * KP / 2;   // 8,798,208 floats
    u16* sigTL = (u16*)f;  f += (size_t)NBC * N * KP / 2;
    u16* AHp   = (u16*)f;  f += (size_t)N * KP / 2;         // 274,944
    u16* ALp   = (u16*)f;  f += (size_t)N * KP / 2;
    float* u    = f;  f += (size_t)B * E;                   // 732,224
    float* rhs  = f;  f += (size_t)B * N * T;               // 549,888
    float* lhs  = f;  f += (size_t)B * N * T;
    float* a    = f;  f += (size_t)B * N * C;               // 458,240
    float* wv   = f;  f += 11444;
    float* bb   = f;  f += 720;
    float* bsT  = f;  f += (size_t)N * N;                   // 512,656
    float* pmax = f;  f += (size_t)4 * B * 720;             // 184,320
    float* psum = f;  f += (size_t)4 * B * 720;
    float* smax = f;  f += (size_t)B * 720;                 // 46,080
    float* sinv = f;  f += (size_t)B * 720;

    k_pre<<<(E + 255) / 256, 256, 0, stream>>>(W_flat, bias, W3, wv, bb);
    k_u<<<(B * E + 255) / 256, 256, 0, stream>>>(vals, W1, u);
    k_rhs<<<(B * N * T + 255) / 256, 256, 0, stream>>>(vals, wv, bb, rhs);
    k_a<<<(B * N * C + 255) / 256, 256, 0, stream>>>(u, W_flat, bias, W1, a);
    k_lhs<<<(B * N * T + 255) / 256, 256, 0, stream>>>(a, W2, lhs);
    k_bsT<<<(N * N + 255) / 256, 256, 0, stream>>>(bs, bsT);
    k_preA<<<(N * KP + 255) / 256, 256, 0, stream>>>(Vs, AHp, ALp);

    for (int c = 0; c < 2; ++c) {
        int b0 = c * NBC;
        dim3 gp(3, (N + 15) / 16, NBC);
        k_prod2<<<gp, 256, 0, stream>>>(lhs, rhs, bsT, sigTH, sigTL, b0);
        dim3 gg((N + 127) / 128, (N + 127) / 128, NBC);
        k_mfma<<<gg, 256, 0, stream>>>(AHp, ALp, sigTH, sigTL, out, b0);
    }

    dim3 gs((N + 255) / 256, B, 4);
    k_stats2<<<gs, 256, 0, stream>>>(out, pmax, psum);
    k_comb<<<(B * N + 255) / 256, 256, 0, stream>>>(pmax, psum, smax, sinv);
    size_t nv = (size_t)B * N * (N / 2);
    k_norm2<<<(int)((nv + 255) / 256), 256, 0, stream>>>(out, smax, sinv);
}

// Round 3
// 428.631 us; speedup vs baseline: 2.7957x; 1.2826x over previous
//
#include <hip/hip_runtime.h>
#include <cstdint>

using u16 = unsigned short;
using f16 = _Float16;

// Problem constants
static constexpr int N = 716;
static constexpr int T = 12;
static constexpr int C = 10;
static constexpr int B = 64;
static constexpr int E = 11441;

static constexpr int KP = 768;           // padded contraction dim (multiple of 64)
static constexpr int BK = 64;            // K-step
static constexpr int NSTEP = KP / BK;    // 12

typedef __attribute__((ext_vector_type(8))) f16 f16x8;
typedef __attribute__((ext_vector_type(4))) float f32x4;

__device__ __forceinline__ int node_off(int n) {
    int q = n / 17, r = n % 17;
    return 8 * n + 136 * q + (r * (r - 1)) / 2;
}

typedef const __attribute__((address_space(1))) unsigned int* gp1_t;
typedef __attribute__((address_space(3))) unsigned int* lp3_t;
__device__ __forceinline__ void gload16(const void* g, void* l) {
    __builtin_amdgcn_global_load_lds((gp1_t)g, (lp3_t)l, 16, 0, 0);
}

// ---------------- small prologue kernels ----------------
__global__ void k_pre(const float* __restrict__ W_flat, const float* __restrict__ bias,
                      const float* __restrict__ W3, float* __restrict__ wv, float* __restrict__ bb) {
    int i = blockIdx.x * blockDim.x + threadIdx.x;
    float w3[C];
#pragma unroll
    for (int c = 0; c < C; ++c) w3[c] = W3[c];
    if (i < E) {
        float s = 0.f;
#pragma unroll
        for (int c = 0; c < C; ++c) s += w3[c] * W_flat[c * E + i];
        wv[i] = s;
    }
    if (i < N) {
        float s = 0.f;
#pragma unroll
        for (int c = 0; c < C; ++c) s += w3[c] * bias[i * C + c];
        bb[i] = s;
    }
}

__global__ void k_u(const float* __restrict__ vals, const float* __restrict__ W1,
                    float* __restrict__ u) {
    int i = blockIdx.x * blockDim.x + threadIdx.x;
    if (i >= B * E) return;
    int b = i / E, e = i - b * E;
    const float* p = vals + (size_t)b * T * E + e;
    float s = 0.f;
#pragma unroll
    for (int t = 0; t < T; ++t) s += p[(size_t)t * E] * W1[t];
    u[i] = s;
}

__global__ void k_rhs(const float* __restrict__ vals, const float* __restrict__ wv,
                      const float* __restrict__ bb, float* __restrict__ rhs) {
    int i = blockIdx.x * blockDim.x + threadIdx.x;
    if (i >= B * N * T) return;
    int t = i % T;
    int bn = i / T;
    int n = bn % N;
    int b = bn / N;
    int off = node_off(n);
    int deg = 8 + (n % 17);
    const float* p = vals + (size_t)b * T * E + (size_t)t * E + off;
    const float* w = wv + off;
    float s = bb[n];
    for (int e = 0; e < deg; ++e) s += p[e] * w[e];
    rhs[i] = s;
}

__global__ void k_a(const float* __restrict__ u, const float* __restrict__ W_flat,
                    const float* __restrict__ bias, const float* __restrict__ W1,
                    float* __restrict__ a) {
    int i = blockIdx.x * blockDim.x + threadIdx.x;
    if (i >= B * N * C) return;
    int c = i % C;
    int bn = i / C;
    int n = bn % N;
    int b = bn / N;
    float S1 = 0.f;
#pragma unroll
    for (int t = 0; t < T; ++t) S1 += W1[t];
    int off = node_off(n);
    int deg = 8 + (n % 17);
    const float* up = u + (size_t)b * E + off;
    const float* wp = W_flat + (size_t)c * E + off;
    float s = bias[n * C + c] * S1;
    for (int e = 0; e < deg; ++e) s += up[e] * wp[e];
    a[i] = s;
}

__global__ void k_lhs(const float* __restrict__ a, const float* __restrict__ W2,
                      float* __restrict__ lhs) {
    int i = blockIdx.x * blockDim.x + threadIdx.x;
    if (i >= B * N * T) return;
    int t = i % T;
    int bn = i / T;
    float s = 0.f;
#pragma unroll
    for (int c = 0; c < C; ++c) s += a[(size_t)bn * C + c] * W2[c * T + t];
    lhs[i] = s;
}

// ---------------- bsT[j][i] = bs[i][j] ----------------
__global__ void k_bsT(const float* __restrict__ bs, float* __restrict__ bsT) {
    int idx = blockIdx.x * blockDim.x + threadIdx.x;
    if (idx >= N * N) return;
    int j = idx / N, i = idx - j * N;
    bsT[(size_t)j * N + i] = bs[(size_t)i * N + j];
}

// ---------------- A planes: Vs -> f16 hi/lo, [716][768], zero pad ----------------
__global__ void k_preA(const float* __restrict__ Vs, f16* __restrict__ AH, f16* __restrict__ AL) {
    int idx = blockIdx.x * blockDim.x + threadIdx.x;
    if (idx >= N * KP) return;
    int n = idx / KP, ic = idx - n * KP;
    float v = (ic < N) ? Vs[(size_t)n * N + ic] : 0.f;
    f16 hi = (f16)v;
    AH[idx] = hi;
    AL[idx] = (f16)(v - (float)hi);
}

// ---------------- rs[n] = sum_i Vs[n,i] (for the sig-0.5 shift correction) ------
__global__ void k_rows(const float* __restrict__ Vs, float* __restrict__ rs) {
    int n = blockIdx.x;
    int lane = threadIdx.x;            // 64 threads
    float s = 0.f;
    for (int i = lane; i < N; i += 64) s += Vs[(size_t)n * N + i];
#pragma unroll
    for (int o = 32; o >= 1; o >>= 1) s += __shfl_down(s, o);
    if (lane == 0) rs[n] = s;
}

// ---------------- sigT plane: T16[b][j][i] = sigmoid(dot(lhs[i],rhs[j]) + bs[i][j]) - 0.5
__global__ void __launch_bounds__(256) k_prod2(const float* __restrict__ lhs,
                                               const float* __restrict__ rhs,
                                               const float* __restrict__ bsT,
                                               f16* __restrict__ T16) {
    __shared__ float rl[16][12];
    int tid = threadIdx.x;
    int b = blockIdx.z;
    int j0 = blockIdx.y * 16;
    int i = blockIdx.x * 256 + tid;     // 0..767
    if (tid < 192) {
        int jj = tid / 12, t = tid - jj * 12;
        int j = j0 + jj;
        rl[jj][t] = (j < N) ? rhs[((size_t)b * N + j) * T + t] : 0.f;
    }
    __syncthreads();
    float l[12];
    bool live = (i < N);
    if (live) {
        const float4* lp = (const float4*)(lhs + ((size_t)b * N + i) * T);
        float4 a0 = lp[0], a1 = lp[1], a2 = lp[2];
        l[0] = a0.x; l[1] = a0.y; l[2] = a0.z; l[3] = a0.w;
        l[4] = a1.x; l[5] = a1.y; l[6] = a1.z; l[7] = a1.w;
        l[8] = a2.x; l[9] = a2.y; l[10] = a2.z; l[11] = a2.w;
    }
#pragma unroll
    for (int jj = 0; jj < 16; ++jj) {
        int j = j0 + jj;
        if (j >= N) break;
        size_t dst = ((size_t)b * N + j) * KP + i;
        if (live) {
            float s = bsT[(size_t)j * N + i];
#pragma unroll
            for (int t = 0; t < T; ++t) s = fmaf(l[t], rl[jj][t], s);
            float v = 1.f / (1.f + __expf(-s)) - 0.5f;
            T16[dst] = (f16)v;
        } else {
            T16[dst] = (f16)0.f;
        }
    }
}

// ---------------- split-f16 MFMA GEMM + fused partial softmax stats --------------
// S[b][n][j] = sum_i Vs[n][i]*sigc[b][i][j] + 0.5*rs[n]
// A = Vs f16 hi/lo [716][KP]; B^T = sigc f16 [B][716][KP].
// 128x128 tile, BK=64, 4 waves (2x2), 2 MFMAs per fragment (AH*B + AL*B).
__global__ void __launch_bounds__(256, 3)
k_mfma(const f16* __restrict__ AH, const f16* __restrict__ AL,
       const f16* __restrict__ Bp, const float* __restrict__ rs,
       float* __restrict__ S, float* __restrict__ pmax, float* __restrict__ psum) {
    __shared__ f16 lds[3][128 * BK];    // 3 planes x 16 KB = 48 KB
    __shared__ float smx[2][2][64];
    __shared__ float ssm[2][2][64];
    const int tid = threadIdx.x;
    const int bz = blockIdx.z;
    const int nt = blockIdx.y, jt = blockIdx.x;
    const int n0 = nt * 128, j0 = jt * 128;
    const int lane = tid & 63;
    const int wid = tid >> 6;
    const int wr = wid >> 1, wc = wid & 1;
    const int r = lane & 15, h = lane >> 4;

    const f16* srcB = Bp + (size_t)bz * N * KP;

    // staging: LDS byte = q*4096 + tid*16 -> row = q*32 + tid/8, col-byte = (tid%8)*16
    // source col-byte = cb ^ ((row&7)<<4)  (inverse of read-side swizzle)
    const int cb_sw = ((tid & 7) * 16) ^ (((tid >> 3) & 7) * 16);
    const int row_base = tid >> 3;

    f32x4 acc[4][4] = {};

    for (int step = 0; step < NSTEP; ++step) {
        const int mb = step * (BK * 2);   // byte offset along a row
#pragma unroll
        for (int p = 0; p < 3; ++p) {
            const int rbase = (p < 2) ? n0 : j0;
            const f16* src = (p == 0) ? AH : (p == 1) ? AL : srcB;
#pragma unroll
            for (int q = 0; q < 4; ++q) {
                int lrow = q * 32 + row_base;
                int grow = rbase + lrow;
                if (grow > N - 1) grow = N - 1;   // clamp: harmless data, outputs masked
                const char* g = (const char*)src + (size_t)grow * (KP * 2) + mb + cb_sw;
                gload16(g, (char*)&lds[p][0] + q * 4096 + tid * 16);
            }
        }
        __syncthreads();
#pragma unroll
        for (int kk = 0; kk < 2; ++kk) {
            f16x8 aHf[4], aLf[4], bf[4];
#pragma unroll
            for (int f = 0; f < 4; ++f) {
                int arow = wr * 64 + f * 16 + r;
                int aidx = arow * BK + ((kk * 32 + h * 8) ^ ((arow & 7) * 8));
                aHf[f] = *(const f16x8*)&lds[0][aidx];
                aLf[f] = *(const f16x8*)&lds[1][aidx];
                int brow = wc * 64 + f * 16 + r;
                int bidx = brow * BK + ((kk * 32 + h * 8) ^ ((brow & 7) * 8));
                bf[f] = *(const f16x8*)&lds[2][bidx];
            }
#pragma unroll
            for (int fi = 0; fi < 4; ++fi)
#pragma unroll
                for (int fj = 0; fj < 4; ++fj) {
                    acc[fi][fj] = __builtin_amdgcn_mfma_f32_16x16x32_f16(aHf[fi], bf[fj], acc[fi][fj], 0, 0, 0);
                    acc[fi][fj] = __builtin_amdgcn_mfma_f32_16x16x32_f16(aLf[fi], bf[fj], acc[fi][fj], 0, 0, 0);
                }
        }
        __syncthreads();
    }

    // epilogue: add 0.5*rowsum term, write S, fused per-column partial stats
    float rsv[4][4];
#pragma unroll
    for (int fi = 0; fi < 4; ++fi)
#pragma unroll
        for (int qq = 0; qq < 4; ++qq) {
            int rg = n0 + wr * 64 + fi * 16 + h * 4 + qq;
            rsv[fi][qq] = (rg < N) ? 0.5f * rs[rg] : 0.f;
        }
#pragma unroll
    for (int fi = 0; fi < 4; ++fi)
#pragma unroll
        for (int fj = 0; fj < 4; ++fj)
#pragma unroll
            for (int qq = 0; qq < 4; ++qq) acc[fi][fj][qq] += rsv[fi][qq];

    float* Sb = S + (size_t)bz * N * N;
#pragma unroll
    for (int fi = 0; fi < 4; ++fi) {
        int rg = n0 + wr * 64 + fi * 16 + h * 4;
#pragma unroll
        for (int fj = 0; fj < 4; ++fj) {
            int cg = j0 + wc * 64 + fj * 16 + r;
            if (cg < N) {
#pragma unroll
                for (int qq = 0; qq < 4; ++qq)
                    if (rg + qq < N) Sb[(size_t)(rg + qq) * N + cg] = acc[fi][fj][qq];
            }
        }
    }

    // per-column max and sum(exp(v-max)) over this block's 128 rows
#pragma unroll
    for (int fj = 0; fj < 4; ++fj) {
        float m = -3.0e38f;
#pragma unroll
        for (int fi = 0; fi < 4; ++fi)
#pragma unroll
            for (int qq = 0; qq < 4; ++qq) {
                int rg = n0 + wr * 64 + fi * 16 + h * 4 + qq;
                float v = (rg < N) ? acc[fi][fj][qq] : -3.0e38f;
                m = fmaxf(m, v);
            }
        m = fmaxf(m, __shfl_xor(m, 16));
        m = fmaxf(m, __shfl_xor(m, 32));
        float s = 0.f;
#pragma unroll
        for (int fi = 0; fi < 4; ++fi)
#pragma unroll
            for (int qq = 0; qq < 4; ++qq) {
                int rg = n0 + wr * 64 + fi * 16 + h * 4 + qq;
                if (rg < N) s += __expf(acc[fi][fj][qq] - m);
            }
        s += __shfl_xor(s, 16);
        s += __shfl_xor(s, 32);
        if (lane < 16) {
            smx[wr][wc][fj * 16 + lane] = m;
            ssm[wr][wc][fj * 16 + lane] = s;
        }
    }
    __syncthreads();
    if (tid < 128) {
        int wcc = tid >> 6, c = tid & 63;
        float m0 = smx[0][wcc][c], m1 = smx[1][wcc][c];
        float m = fmaxf(m0, m1);
        float s = ssm[0][wcc][c] * __expf(m0 - m) + ssm[1][wcc][c] * __expf(m1 - m);
        int j = j0 + wcc * 64 + c;
        size_t o = ((size_t)bz * 6 + nt) * 768 + j;
        pmax[o] = m;
        psum[o] = s;
    }
}

// ---------------- combine 6 row-tile partials -> per-(b,j) max & 1/sum ----------
__global__ void k_comb(const float* __restrict__ pmax, const float* __restrict__ psum,
                       float* __restrict__ smax, float* __restrict__ sinv) {
    int i = blockIdx.x * 256 + threadIdx.x;
    if (i >= B * N) return;
    int b = i / N, j = i - b * N;
    float m = -3.0e38f;
#pragma unroll
    for (int c = 0; c < 6; ++c) m = fmaxf(m, pmax[((size_t)b * 6 + c) * 768 + j]);
    float s = 0.f;
#pragma unroll
    for (int c = 0; c < 6; ++c)
        s += psum[((size_t)b * 6 + c) * 768 + j] * __expf(pmax[((size_t)b * 6 + c) * 768 + j] - m);
    smax[(size_t)b * 720 + j] = m;
    sinv[(size_t)b * 720 + j] = 1.f / s;
}

// ---------------- out[b,n,j] = exp(S-max)*inv  (float4, in place) ----------------
__global__ void k_norm2(float* __restrict__ S, const float* __restrict__ smax,
                        const float* __restrict__ sinv) {
    size_t idx = (size_t)blockIdx.x * 256 + threadIdx.x;
    if (idx >= (size_t)B * N * (N / 4)) return;
    int jq = (int)(idx % (N / 4));
    size_t bn = idx / (N / 4);
    int n = (int)(bn % N);
    int b = (int)(bn / N);
    size_t base = ((size_t)b * N + n) * N + (size_t)jq * 4;
    int j = jq * 4;
    float4 v = *(float4*)(S + base);
    float4 mm = *(const float4*)(smax + (size_t)b * 720 + j);
    float4 rr = *(const float4*)(sinv + (size_t)b * 720 + j);
    v.x = __expf(v.x - mm.x) * rr.x;
    v.y = __expf(v.y - mm.y) * rr.y;
    v.z = __expf(v.z - mm.z) * rr.z;
    v.w = __expf(v.w - mm.w) * rr.w;
    *(float4*)(S + base) = v;
}

extern "C" void kernel_launch(void* const* d_in, const int* in_sizes, int n_in,
                              void* d_out, int out_size, void* d_ws, size_t ws_size,
                              hipStream_t stream) {
    const float* vals   = (const float*)d_in[0];  // [B,T,E]
    const float* W_flat = (const float*)d_in[1];  // [C,E]
    const float* bias   = (const float*)d_in[2];  // [N,C]
    const float* W1     = (const float*)d_in[3];  // [T]
    const float* W2     = (const float*)d_in[4];  // [C,T]
    const float* W3     = (const float*)d_in[5];  // [C]
    const float* bs     = (const float*)d_in[6];  // [1,N,N]
    const float* Vs     = (const float*)d_in[7];  // [N,N]
    float* out = (float*)d_out;                   // [B,N,N]

    float* f = (float*)d_ws;
    f16* sigT = (f16*)f;   f += (size_t)B * N * KP / 2;     // 17,596,416 floats
    f16* AHp  = (f16*)f;   f += (size_t)N * KP / 2;         // 137,472
    f16* ALp  = (f16*)f;   f += (size_t)N * KP / 2;
    float* u    = f;  f += (size_t)B * E;                   // 732,224
    float* rhs  = f;  f += (size_t)B * N * T;               // 549,888
    float* lhs  = f;  f += (size_t)B * N * T;
    float* a    = f;  f += (size_t)B * N * C;               // 458,240
    float* wv   = f;  f += 11444;
    float* bb   = f;  f += 720;
    float* bsT  = f;  f += (size_t)N * N;                   // 512,656
    float* rsw  = f;  f += 720;
    float* pmax = f;  f += (size_t)B * 6 * 768;             // 294,912
    float* psum = f;  f += (size_t)B * 6 * 768;
    float* smax = f;  f += (size_t)B * 720;                 // 46,080
    float* sinv = f;  f += (size_t)B * 720;

    k_pre<<<(E + 255) / 256, 256, 0, stream>>>(W_flat, bias, W3, wv, bb);
    k_u<<<(B * E + 255) / 256, 256, 0, stream>>>(vals, W1, u);
    k_rhs<<<(B * N * T + 255) / 256, 256, 0, stream>>>(vals, wv, bb, rhs);
    k_a<<<(B * N * C + 255) / 256, 256, 0, stream>>>(u, W_flat, bias, W1, a);
    k_lhs<<<(B * N * T + 255) / 256, 256, 0, stream>>>(a, W2, lhs);
    k_bsT<<<(N * N + 255) / 256, 256, 0, stream>>>(bs, bsT);
    k_preA<<<(N * KP + 255) / 256, 256, 0, stream>>>(Vs, AHp, ALp);
    k_rows<<<N, 64, 0, stream>>>(Vs, rsw);

    dim3 gp(3, (N + 15) / 16, B);
    k_prod2<<<gp, 256, 0, stream>>>(lhs, rhs, bsT, sigT);

    dim3 gg((N + 127) / 128, (N + 127) / 128, B);
    k_mfma<<<gg, 256, 0, stream>>>(AHp, ALp, sigT, rsw, out, pmax, psum);

    k_comb<<<(B * N + 255) / 256, 256, 0, stream>>>(pmax, psum, smax, sinv);

    size_t nv = (size_t)B * N * (N / 4);
    k_norm2<<<(int)((nv + 255) / 256), 256, 0, stream>>>(out, smax, sinv);
}